// Round 1
// baseline (855.674 us; speedup 1.0000x reference)
//
#include <hip/hip_runtime.h>
#include <hip/hip_bf16.h>

// ---------- types / helpers ----------
typedef __bf16 bf16x8 __attribute__((ext_vector_type(8)));
typedef float  f32x4  __attribute__((ext_vector_type(4)));
typedef unsigned int u32;
typedef u32 u32x4 __attribute__((ext_vector_type(4)));
typedef unsigned short ushort_t;

__device__ inline float bf2f(ushort_t h) {
    union { u32 u; float f; } v; v.u = ((u32)h) << 16; return v.f;
}
__device__ inline ushort_t f2bf(float f) {
    union { float f; u32 u; } v; v.f = f;
    u32 u = v.u;
    return (ushort_t)((u + 0x7fffu + ((u >> 16) & 1u)) >> 16);   // RNE
}
__device__ inline bf16x8 load_bf8(const ushort_t* p) {
    u32x4 u = *reinterpret_cast<const u32x4*>(p);
    return __builtin_bit_cast(bf16x8, u);
}
// dual-dtype loaders for inputs (idx in elements). f32flag=1 -> array is fp32.
__device__ inline bf16x8 load8_in(const void* base, size_t idx, int f32flag) {
    if (!f32flag) return load_bf8((const ushort_t*)base + idx);
    const float* pf = (const float*)base + idx;
    f32x4 a = *reinterpret_cast<const f32x4*>(pf);
    f32x4 b = *reinterpret_cast<const f32x4*>(pf + 4);
    bf16x8 r;
#pragma unroll
    for (int j = 0; j < 4; ++j) { r[j] = (__bf16)a[j]; r[4 + j] = (__bf16)b[j]; }
    return r;
}
__device__ inline float ld_in(const void* base, size_t idx, int f32flag) {
    return f32flag ? ((const float*)base)[idx] : bf2f(((const ushort_t*)base)[idx]);
}

#define XT_STRIDE 264   // attn-out LDS row stride in ushorts (padded)

// ---------- kernel 0: per-array dtype detector (unchanged) ----------
__global__ __launch_bounds__(256) void detect_kernel(const u32* __restrict__ d, int n,
                                                     int* __restrict__ flag) {
    const int t = threadIdx.x;
    int cn = 0, co = 0;
    for (int i = t; i < n; i += 256) {
        const u32 w = d[i];
        const u32 e  = (w >> 7) & 0xFF;
        const u32 fe = (w >> 23) & 0xFF;
        cn += (e >= 100 && e <= 135) ? 1 : 0;
        co += (((w & 0xFFFFu) == 0u) && fe >= 100 && fe <= 140) ? 1 : 0;
    }
    __shared__ int sn[256], so[256];
    sn[t] = cn; so[t] = co; __syncthreads();
    for (int o = 128; o; o >>= 1) {
        if (t < o) { sn[t] += sn[t + o]; so[t] += so[t + o]; }
        __syncthreads();
    }
    if (t == 0) {
        const int CN = sn[0], CO = so[0];
        const int is_f32 = (2 * CN < n) && ((2 * CO > n) || (20 * CN > n));
        *flag = is_f32 ? 1 : 0;
    }
}

// flags layout: [0]=q_emb [1]=s_emb [3]=W_lin [4]=b_lin [5]=W_out [6]=b_out [7]=ln_g [8]=ln_b
__device__ inline int f_of(const int* flags, int i) { return i < 0 ? 0 : flags[i]; }
__device__ inline int out_f32(const int* flags) {
    return flags[0] | flags[1] | flags[3] | flags[4] | flags[5] | flags[6] | flags[7] | flags[8];
}

// ---------- swizzled proj-tile addressing ----------
// tile: 80 rows x 128 ch bf16 (20480 B). XOR-swizzle spreads the 256B-stride
// column reads of the attention phase across banks. Element index:
__device__ inline int tidx(int row, int ch) { return row * 128 + (ch ^ ((row & 7) << 3)); }

// ---------- per-dilation projection into LDS tile (rows s0-8 .. s0+71, clamped) ----------
// tile[row][n] = X[bb*2048 + clamp(s0-8+row)][dil*128 + k] @ W[dil][n][k] + b[dil][n]
// Clamped halo rows hold duplicates of row 0/2047; attention masks them (sp bounds),
// so their values are never consumed.
__device__ __forceinline__ void proj_tile(
    const void* __restrict__ X, int xf, int dil, int bb, int s0,
    const void* __restrict__ W, size_t lw, int wfl,
    const void* __restrict__ Bv, size_t lb, int bfl,
    ushort_t* tile, int wave, int lane)
{
    const int l15 = lane & 15, quad = lane >> 4;
    const int n_off = wave * 32;                    // 4 waves cover N=128
    f32x4 acc[5][2] = {};
    for (int kc = 0; kc < 4; ++kc) {
        bf16x8 a[5], b[2];
#pragma unroll
        for (int mt = 0; mt < 5; ++mt) {            // M=80 rows
            int s = s0 - 8 + mt * 16 + l15;
            s = s < 0 ? 0 : (s > 2047 ? 2047 : s);
            a[mt] = load8_in(X, ((size_t)bb * 2048 + s) * 256 + dil * 128 + kc * 32 + quad * 8, xf);
        }
#pragma unroll
        for (int nt = 0; nt < 2; ++nt)
            b[nt] = load8_in(W, lw + (size_t)dil * 16384 +
                             (size_t)(n_off + nt * 16 + l15) * 128 + kc * 32 + quad * 8, wfl);
#pragma unroll
        for (int mt = 0; mt < 5; ++mt)
#pragma unroll
            for (int nt = 0; nt < 2; ++nt)
                acc[mt][nt] = __builtin_amdgcn_mfma_f32_16x16x32_bf16(a[mt], b[nt], acc[mt][nt], 0, 0, 0);
    }
#pragma unroll
    for (int nt = 0; nt < 2; ++nt) {
        const int ncol = n_off + nt * 16 + l15;
        const float bias = ld_in(Bv, lb + dil * 128 + ncol, bfl);
#pragma unroll
        for (int mt = 0; mt < 5; ++mt)
#pragma unroll
            for (int r = 0; r < 4; ++r) {
                const int row = mt * 16 + quad * 4 + r;
                tile[tidx(row, ncol)] = f2bf(acc[mt][nt][r] + bias);
            }
    }
}

// ---------- fully fused stage: proj + dilated attention + out-proj + bias + residual + LN ----------
// One kernel per transformer stage. Block owns 64 rows; projects an 80-row halo tile
// per dilation into LDS, runs attention from LDS, then the 256-wide output GEMM + LN.
// sepv=1 (stage C): V tile is re-projected from Xv between scores and PV (p held in regs).
__global__ __launch_bounds__(256) void stage_kernel(
    const void* __restrict__ Xq, int xqi,
    const void* __restrict__ Xv, int xvi, int sepv,
    const void* __restrict__ Wl, size_t lwl,
    const void* __restrict__ bl, size_t lbl,
    const void* __restrict__ Wo, size_t lwo,
    const void* __restrict__ bo, size_t lbo,
    const void* __restrict__ G, const void* __restrict__ Bt, size_t lg,
    const void* __restrict__ R, int ri,
    void* __restrict__ H, int h_out,
    void* __restrict__ probs_base,
    const int* __restrict__ flags)
{
    // LDS arena: tile 20480 B | xt 64*264*2 = 33792 B  -> 54272 B (3 blocks/CU).
    // lsum/lsq alias the tile region (tile is dead once the out-GEMM starts).
    __shared__ __align__(16) char smem[54272];
    ushort_t* tile = (ushort_t*)smem;
    ushort_t* xt   = (ushort_t*)(smem + 20480);

    const int xqf = f_of(flags, xqi), xvf = f_of(flags, xvi);
    const int wlf = flags[3], blf = flags[4];
    const int wof = flags[5], bof = flags[6], gf = flags[7], btf = flags[8];
    const int rf  = f_of(flags, ri);
    const int og  = out_f32(flags);
    const int of  = h_out ? og : 0;

    const int tid  = threadIdx.x;
    const int wave = tid >> 6, lane = tid & 63;
    const int l15  = lane & 15, quad = lane >> 4;
    const int m0   = blockIdx.x * 64;
    const int bb   = m0 >> 11;
    const int s0   = m0 & 2047;
    const float scale = 0.17677669529663687f;   // 32^-0.5

    // attention task mapping: r = row-in-block (lane), g = head-in-split (wave)
    const int r = lane, g = wave;

    for (int dil = 0; dil < 2; ++dil) {
        if (dil) __syncthreads();                 // prev tile fully consumed
        proj_tile(Xq, xqf, dil, bb, s0, Wl, lwl, wlf, bl, lbl, blf, tile, wave, lane);
        __syncthreads();                          // Q/K tile ready

        const int dila = dil ? 1 : 3;             // DILATIONS = (3,1)
        const int s = s0 + r;

        float qv[4][8];
#pragma unroll
        for (int h = 0; h < 4; ++h) {
            bf16x8 t = load_bf8(&tile[tidx(8 + r, g * 8 + h * 32)]);
#pragma unroll
            for (int j = 0; j < 8; ++j) qv[h][j] = (float)t[j];
        }
        float sc[5];
#pragma unroll
        for (int kk = 0; kk < 5; ++kk) {
            const int sp = s + (kk - 2) * dila;
            float a = 0.f;
            if (sp >= 0 && sp < 2048) {           // OOB -> score 0 (matches zero-pad unfold)
                const int krow = 8 + r + (kk - 2) * dila;
#pragma unroll
                for (int h = 0; h < 4; ++h) {
                    bf16x8 t = load_bf8(&tile[tidx(krow, g * 8 + h * 32)]);
#pragma unroll
                    for (int j = 0; j < 8; ++j) a += qv[h][j] * (float)t[j];
                }
                a *= scale;
            }
            sc[kk] = a;
        }
        float mx = sc[0];
#pragma unroll
        for (int kk = 1; kk < 5; ++kk) mx = fmaxf(mx, sc[kk]);
        float p[5], sum = 0.f;
#pragma unroll
        for (int kk = 0; kk < 5; ++kk) { p[kk] = __expf(sc[kk] - mx); sum += p[kk]; }
        const float inv = 1.f / sum;
#pragma unroll
        for (int kk = 0; kk < 5; ++kk) p[kk] *= inv;

        if (probs_base != nullptr) {
            const size_t pb = 16777216 + ((size_t)((bb * 8 + dil * 4 + g) * 2048 + s)) * 5;
            if (og) {
                float* pp = (float*)probs_base;
#pragma unroll
                for (int kk = 0; kk < 5; ++kk) pp[pb + kk] = p[kk];
            } else {
                ushort_t* pp = (ushort_t*)probs_base;
#pragma unroll
                for (int kk = 0; kk < 5; ++kk) pp[pb + kk] = f2bf(p[kk]);
            }
        }

        if (sepv) {                               // stage C: overwrite tile with V projection
            __syncthreads();                      // all score reads done
            proj_tile(Xv, xvf, dil, bb, s0, Wl, lwl, wlf, bl, lbl, blf, tile, wave, lane);
            __syncthreads();                      // V tile ready
        }

        float o[4][8] = {};
#pragma unroll
        for (int kk = 0; kk < 5; ++kk) {
            const int sp = s + (kk - 2) * dila;
            if (sp < 0 || sp >= 2048) continue;
            const int vrow = 8 + r + (kk - 2) * dila;
#pragma unroll
            for (int h = 0; h < 4; ++h) {
                bf16x8 t = load_bf8(&tile[tidx(vrow, g * 8 + h * 32)]);
#pragma unroll
                for (int j = 0; j < 8; ++j) o[h][j] += p[kk] * (float)t[j];
            }
        }
        // pack attn result to xt (channel dil*128 + g*32 + d2, value o[d2&3][d2>>2])
        ushort_t* op = &xt[r * XT_STRIDE + dil * 128 + g * 32];
#pragma unroll
        for (int c = 0; c < 4; ++c) {
            u32x4 w;
#pragma unroll
            for (int t4 = 0; t4 < 4; ++t4) {
                const int d2a = c * 8 + t4 * 2, d2b = d2a + 1;
                const u32 lo = f2bf(o[d2a & 3][d2a >> 2]);
                const u32 hi = f2bf(o[d2b & 3][d2b >> 2]);
                w[t4] = lo | (hi << 16);
            }
            *reinterpret_cast<u32x4*>(op + c * 8) = w;
        }
    }
    __syncthreads();                              // xt complete; tile now dead

    // ---- output GEMM (K=256) + bias + residual + LN epilogue ----
    float (*lsum)[64] = (float(*)[64])(smem);          // alias over dead tile
    float (*lsq)[64]  = (float(*)[64])(smem + 1024);

    const int n_off = wave * 64;

    f32x4 acc[4][4] = {};
    for (int kc = 0; kc < 8; ++kc) {
        bf16x8 a[4], b[4];
#pragma unroll
        for (int mt = 0; mt < 4; ++mt)
            a[mt] = load_bf8(&xt[(mt * 16 + l15) * XT_STRIDE + kc * 32 + quad * 8]);
#pragma unroll
        for (int nt = 0; nt < 4; ++nt)
            b[nt] = load8_in(Wo, lwo + (size_t)(n_off + nt * 16 + l15) * 256 + kc * 32 + quad * 8, wof);
#pragma unroll
        for (int mt = 0; mt < 4; ++mt)
#pragma unroll
            for (int nt = 0; nt < 4; ++nt)
                acc[mt][nt] = __builtin_amdgcn_mfma_f32_16x16x32_bf16(a[mt], b[nt], acc[mt][nt], 0, 0, 0);
    }

    float bias[4];
#pragma unroll
    for (int nt = 0; nt < 4; ++nt) bias[nt] = ld_in(bo, lbo + n_off + nt * 16 + l15, bof);

    float psum[4][4] = {}, psq[4][4] = {};
#pragma unroll
    for (int mt = 0; mt < 4; ++mt) {
#pragma unroll
        for (int rr = 0; rr < 4; ++rr) {
            const size_t rrow = (size_t)(m0 + mt * 16 + quad * 4 + rr) * 256 + l15;
#pragma unroll
            for (int nt = 0; nt < 4; ++nt) {
                float v = acc[mt][nt][rr] + bias[nt] + ld_in(R, rrow + n_off + nt * 16, rf);
                acc[mt][nt][rr] = v;
                psum[mt][rr] += v;
                psq[mt][rr]  += v * v;
            }
        }
    }
#pragma unroll
    for (int off = 1; off <= 8; off <<= 1) {
#pragma unroll
        for (int mt = 0; mt < 4; ++mt)
#pragma unroll
            for (int rr = 0; rr < 4; ++rr) {
                psum[mt][rr] += __shfl_xor(psum[mt][rr], off);
                psq[mt][rr]  += __shfl_xor(psq[mt][rr],  off);
            }
    }
    if (l15 == 0) {
#pragma unroll
        for (int mt = 0; mt < 4; ++mt)
#pragma unroll
            for (int rr = 0; rr < 4; ++rr) {
                const int row = mt * 16 + quad * 4 + rr;
                lsum[wave][row] = psum[mt][rr];
                lsq[wave][row]  = psq[mt][rr];
            }
    }
    __syncthreads();

    float gl[4], blv[4];
#pragma unroll
    for (int nt = 0; nt < 4; ++nt) {
        gl[nt]  = ld_in(G,  lg + n_off + nt * 16 + l15, gf);
        blv[nt] = ld_in(Bt, lg + n_off + nt * 16 + l15, btf);
    }
#pragma unroll
    for (int mt = 0; mt < 4; ++mt) {
#pragma unroll
        for (int rr = 0; rr < 4; ++rr) {
            const int row = mt * 16 + quad * 4 + rr;
            const float sm = lsum[0][row] + lsum[1][row] + lsum[2][row] + lsum[3][row];
            const float q2 = lsq[0][row]  + lsq[1][row]  + lsq[2][row]  + lsq[3][row];
            const float mu  = sm * (1.f / 256.f);
            const float var = q2 * (1.f / 256.f) - mu * mu;
            const float rs  = rsqrtf(var + 1e-5f);
            const size_t hrow = (size_t)(m0 + row) * 256 + l15;
#pragma unroll
            for (int nt = 0; nt < 4; ++nt) {
                const float hv = (acc[mt][nt][rr] - mu) * rs * gl[nt] + blv[nt];
                if (of) ((float*)H)[hrow + n_off + nt * 16] = hv;
                else    ((ushort_t*)H)[hrow + n_off + nt * 16] = f2bf(hv);
            }
        }
    }
}

// ---------- launch ----------
extern "C" void kernel_launch(void* const* d_in, const int* in_sizes, int n_in,
                              void* d_out, int out_size, void* d_ws, size_t ws_size,
                              hipStream_t stream) {
    const void* q_emb = d_in[0];
    const void* s_emb = d_in[1];
    const void* W_lin = d_in[3];   // (3,2,128,128) layer stride 32768 elems
    const void* b_lin = d_in[4];   // (3,2,128)     layer stride 256
    const void* W_out = d_in[5];   // (3,256,256)   layer stride 65536
    const void* b_out = d_in[6];   // (3,256)       layer stride 256
    const void* ln_g  = d_in[7];
    const void* ln_b  = d_in[8];

    const size_t SLOT = 16777216;
    int*      flags = (int*)d_ws;                      // 16 ints
    ushort_t* SA = (ushort_t*)((char*)d_ws + 256);     // hq (bf16)
    ushort_t* SB = SA + SLOT;                          // hs (bf16)
    // d_ws footprint: 256 B + 2 x 33.55 MB = 67.1 MB

    const dim3 blk(256);
    detect_kernel<<<1, blk, 0, stream>>>((const u32*)q_emb, 16384, flags + 0);
    detect_kernel<<<1, blk, 0, stream>>>((const u32*)s_emb, 16384, flags + 1);
    detect_kernel<<<1, blk, 0, stream>>>((const u32*)W_lin, 16384, flags + 3);
    detect_kernel<<<1, blk, 0, stream>>>((const u32*)b_lin,   384, flags + 4);
    detect_kernel<<<1, blk, 0, stream>>>((const u32*)W_out, 16384, flags + 5);
    detect_kernel<<<1, blk, 0, stream>>>((const u32*)b_out,   384, flags + 6);
    detect_kernel<<<1, blk, 0, stream>>>((const u32*)ln_g,    384, flags + 7);
    detect_kernel<<<1, blk, 0, stream>>>((const u32*)ln_b,    384, flags + 8);

    // ---- stage A: hq = LN(q_emb + mha(q_emb)) -> SA (bf16)
    stage_kernel<<<1024, blk, 0, stream>>>(q_emb, 0, q_emb, 0, 0,
        W_lin, 0, b_lin, 0, W_out, 0, b_out, 0, ln_g, ln_b, 0,
        q_emb, 0, SA, 0, nullptr, flags);
    // ---- stage B: hs = LN(s_emb + mha(s_emb)) -> SB (bf16), probs -> d_out[16777216..]
    stage_kernel<<<1024, blk, 0, stream>>>(s_emb, 1, s_emb, 1, 0,
        W_lin, 32768, b_lin, 256, W_out, 65536, b_out, 256, ln_g, ln_b, 256,
        s_emb, 1, SB, 0, d_out, flags);
    // ---- stage C: z = LN(hq + mha(q=k=hq, v=hs)) -> d_out (out dtype)
    stage_kernel<<<1024, blk, 0, stream>>>(SA, -1, SB, -1, 1,
        W_lin, 65536, b_lin, 512, W_out, 131072, b_out, 512, ln_g, ln_b, 512,
        SA, -1, d_out, 1, nullptr, flags);
}

// Round 2
// 621.836 us; speedup vs baseline: 1.3760x; 1.3760x over previous
//
#include <hip/hip_runtime.h>
#include <hip/hip_bf16.h>

// ---------- types / helpers ----------
typedef __bf16 bf16x8 __attribute__((ext_vector_type(8)));
typedef float  f32x4  __attribute__((ext_vector_type(4)));
typedef unsigned int u32;
typedef u32 u32x4 __attribute__((ext_vector_type(4)));
typedef unsigned short ushort_t;

__device__ inline float bf2f(ushort_t h) {
    union { u32 u; float f; } v; v.u = ((u32)h) << 16; return v.f;
}
__device__ inline ushort_t f2bf(float f) {
    union { float f; u32 u; } v; v.f = f;
    u32 u = v.u;
    return (ushort_t)((u + 0x7fffu + ((u >> 16) & 1u)) >> 16);   // RNE
}
__device__ inline bf16x8 load_bf8(const ushort_t* p) {
    u32x4 u = *reinterpret_cast<const u32x4*>(p);
    return __builtin_bit_cast(bf16x8, u);
}
// dual-dtype loaders for inputs (idx in elements). f32flag=1 -> array is fp32.
__device__ inline bf16x8 load8_in(const void* base, size_t idx, int f32flag) {
    if (!f32flag) return load_bf8((const ushort_t*)base + idx);
    const float* pf = (const float*)base + idx;
    f32x4 a = *reinterpret_cast<const f32x4*>(pf);
    f32x4 b = *reinterpret_cast<const f32x4*>(pf + 4);
    bf16x8 r;
#pragma unroll
    for (int j = 0; j < 4; ++j) { r[j] = (__bf16)a[j]; r[4 + j] = (__bf16)b[j]; }
    return r;
}
__device__ inline float ld_in(const void* base, size_t idx, int f32flag) {
    return f32flag ? ((const float*)base)[idx] : bf2f(((const ushort_t*)base)[idx]);
}

// ---------- swizzled layouts ----------
// Projected arrays (SC, V-projected SB) live in a row-keyed XOR-swizzled layout:
//   element (row, ch) stored at row*256 + (ch ^ ((row&15)<<3)).
// The XOR acts on 8-element (16B) granularity, so 16B vector IO is preserved.
// Local proj tiles use local row (m0 % 16 == 0 -> same key):
__device__ inline int pofs(int row, int ch) { return row * 256 + (ch ^ ((row & 15) << 3)); }
// Fused attention tile: tr = global_row - (s0-8), s0 % 16 == 0 -> key (tr+8)&15:
__device__ inline int tofs(int tr, int ch) { return tr * 256 + (ch ^ (((tr + 8) & 15) << 3)); }

// ---------- kernel 0: per-array dtype detector ----------
__global__ __launch_bounds__(256) void detect_kernel(const u32* __restrict__ d, int n,
                                                     int* __restrict__ flag) {
    const int t = threadIdx.x;
    int cn = 0, co = 0;
    for (int i = t; i < n; i += 256) {
        const u32 w = d[i];
        const u32 e  = (w >> 7) & 0xFF;
        const u32 fe = (w >> 23) & 0xFF;
        cn += (e >= 100 && e <= 135) ? 1 : 0;
        co += (((w & 0xFFFFu) == 0u) && fe >= 100 && fe <= 140) ? 1 : 0;
    }
    __shared__ int sn[256], so[256];
    sn[t] = cn; so[t] = co; __syncthreads();
    for (int o = 128; o; o >>= 1) {
        if (t < o) { sn[t] += sn[t + o]; so[t] += so[t + o]; }
        __syncthreads();
    }
    if (t == 0) {
        const int CN = sn[0], CO = so[0];
        const int is_f32 = (2 * CN < n) && ((2 * CO > n) || (20 * CN > n));
        *flag = is_f32 ? 1 : 0;
    }
}

// flags layout: [0]=q_emb [1]=s_emb [3]=W_lin [4]=b_lin [5]=W_out [6]=b_out [7]=ln_g [8]=ln_b
__device__ inline int f_of(const int* flags, int i) { return i < 0 ? 0 : flags[i]; }
__device__ inline int out_f32(const int* flags) {
    return flags[0] | flags[1] | flags[3] | flags[4] | flags[5] | flags[6] | flags[7] | flags[8];
}

// ---------- kernel 1: per-dilation projection (LDS-staged both directions) ----------
// Y[row][ch] (swizzled layout) = X[row][dil*128+k] @ W[dil][n][k] + b[dil][n]
// X row-major (dtype by flag); Y bf16 swizzled. In-place safe when X==Y (block-local rows,
// stage-in completes before any store).
__global__ __launch_bounds__(256, 4) void proj_kernel(
    const void* __restrict__ X, int xi,
    const void* __restrict__ W, size_t lw,
    const void* __restrict__ Bv, size_t lb,
    ushort_t* __restrict__ Y, const int* __restrict__ flags)
{
    __shared__ ushort_t tile[64 * 256];   // 32 KB
    const int xf  = f_of(flags, xi);
    const int wf  = flags[3], bfl = flags[4];
    const int tid = threadIdx.x;
    const int m0  = blockIdx.x * 64;

    // stage in: 64 rows x 32 chunks(16B) = 2048 chunks, coalesced, convert to bf16, swizzle
#pragma unroll
    for (int i = 0; i < 8; ++i) {
        const int c = tid + 256 * i;
        const int row = c >> 5, cc = c & 31;
        bf16x8 v = load8_in(X, (size_t)(m0 + row) * 256 + cc * 8, xf);
        *reinterpret_cast<u32x4*>(&tile[pofs(row, cc * 8)]) = __builtin_bit_cast(u32x4, v);
    }
    __syncthreads();

    const int wave = tid >> 6, lane = tid & 63;
    const int dil  = wave >> 1;
    const int n_off = (wave & 1) * 64;
    const int l15  = lane & 15, quad = lane >> 4;

    f32x4 acc[4][4] = {};
    for (int kc = 0; kc < 4; ++kc) {
        bf16x8 a[4], b[4];
#pragma unroll
        for (int mt = 0; mt < 4; ++mt)
            a[mt] = load_bf8(&tile[pofs(mt * 16 + l15, dil * 128 + kc * 32 + quad * 8)]);
#pragma unroll
        for (int nt = 0; nt < 4; ++nt)
            b[nt] = load8_in(W, lw + (size_t)dil * 16384 +
                             (size_t)(n_off + nt * 16 + l15) * 128 + kc * 32 + quad * 8, wf);
#pragma unroll
        for (int mt = 0; mt < 4; ++mt)
#pragma unroll
            for (int nt = 0; nt < 4; ++nt)
                acc[mt][nt] = __builtin_amdgcn_mfma_f32_16x16x32_bf16(a[mt], b[nt], acc[mt][nt], 0, 0, 0);
    }
    __syncthreads();   // input tile consumed; reuse for output pack

#pragma unroll
    for (int nt = 0; nt < 4; ++nt) {
        const int ncol = n_off + nt * 16 + l15;
        const float bias = ld_in(Bv, lb + dil * 128 + ncol, bfl);
#pragma unroll
        for (int mt = 0; mt < 4; ++mt)
#pragma unroll
            for (int r = 0; r < 4; ++r) {
                const int row = mt * 16 + quad * 4 + r;
                tile[pofs(row, dil * 128 + ncol)] = f2bf(acc[mt][nt][r] + bias);
            }
    }
    __syncthreads();

    // store out: tile (swizzled) -> Y (same swizzle) is a straight linear copy
#pragma unroll
    for (int i = 0; i < 8; ++i) {
        const int c = tid + 256 * i;
        const int row = c >> 5, cc = c & 31;
        *reinterpret_cast<u32x4*>(Y + (size_t)(m0 + row) * 256 + cc * 8) =
            *reinterpret_cast<const u32x4*>(&tile[row * 256 + cc * 8]);
    }
}

// ---------- kernel 2: fused attention + output proj + bias + residual + LN ----------
// P, V: bf16 swizzled projections (V==P for stages A/B). R row-major residual.
// Attention reads K/V from an LDS-staged 80-row halo tile; results are written back
// into the tile (dil-d output occupies ch half d, which the other dil never reads),
// which then feeds the output GEMM. LDS = 40960 B -> 4 blocks/CU.
__global__ __launch_bounds__(256, 4) void fused_attn_oln_kernel(
    const ushort_t* __restrict__ P, const ushort_t* __restrict__ V,
    const void* __restrict__ R, int ri,
    const void* __restrict__ W, size_t lw,
    const void* __restrict__ Bv, size_t lb,
    const void* __restrict__ G, const void* __restrict__ Bt, size_t lg,
    void* __restrict__ H, int h_out,
    void* __restrict__ probs_base,
    const int* __restrict__ flags)
{
    __shared__ ushort_t tile[80 * 256];   // 40960 B
    // lsum/lsq alias halo rows 0-7 (dead after PV): bytes 0..2047 / 2048..4095
    float (*lsum)[64] = (float (*)[64])(&tile[0]);
    float (*lsq)[64]  = (float (*)[64])(&tile[1024]);

    const int wf = flags[5], bvf = flags[6], gf = flags[7], btf = flags[8];
    const int rf = f_of(flags, ri);
    const int og = out_f32(flags);
    const int of = h_out ? og : 0;

    const int tid  = threadIdx.x;
    const int wave = tid >> 6, lane = tid & 63;
    const int l15  = lane & 15, quad = lane >> 4;
    const int m0   = blockIdx.x * 64;
    const int bb   = m0 >> 11;
    const int s0   = m0 & 2047;
    const size_t rowbase = (size_t)bb * 2048;
    const float scale = 0.17677669529663687f;   // 32^-0.5

    // ---- stage P tile: rows s0-8 .. s0+71 (clamped), straight row copies keep swizzle
#pragma unroll
    for (int i = 0; i < 10; ++i) {
        const int c = tid + 256 * i;          // 2560 chunks total
        const int tr = c >> 5, cc = c & 31;
        int s = s0 - 8 + tr; s = s < 0 ? 0 : (s > 2047 ? 2047 : s);
        *reinterpret_cast<u32x4*>(&tile[tr * 256 + cc * 8]) =
            *reinterpret_cast<const u32x4*>(P + (rowbase + s) * 256 + cc * 8);
    }
    __syncthreads();

    const int r = lane, g = wave;
    const int s = s0 + r;

    // ---- scores + softmax for both dilations (p kept in regs)
    float p2[2][5];
#pragma unroll
    for (int it = 0; it < 2; ++it) {
        const int dil  = it;
        const int dila = dil ? 1 : 3;         // DILATIONS = (3,1)
        const int ch0  = dil * 128 + g * 8;

        float qv[4][8];
#pragma unroll
        for (int h = 0; h < 4; ++h) {
            bf16x8 t = load_bf8(&tile[tofs(8 + r, ch0 + h * 32)]);
#pragma unroll
            for (int j = 0; j < 8; ++j) qv[h][j] = (float)t[j];
        }
        float sc[5];
#pragma unroll
        for (int kk = 0; kk < 5; ++kk) {
            const int sp = s + (kk - 2) * dila;
            float a = 0.f;
            if (sp >= 0 && sp < 2048) {       // OOB -> score 0 (zero-pad unfold)
                const int tr2 = 8 + r + (kk - 2) * dila;
#pragma unroll
                for (int h = 0; h < 4; ++h) {
                    bf16x8 t = load_bf8(&tile[tofs(tr2, ch0 + h * 32)]);
#pragma unroll
                    for (int j = 0; j < 8; ++j) a += qv[h][j] * (float)t[j];
                }
                a *= scale;
            }
            sc[kk] = a;
        }
        float mx = sc[0];
#pragma unroll
        for (int kk = 1; kk < 5; ++kk) mx = fmaxf(mx, sc[kk]);
        float sum = 0.f;
#pragma unroll
        for (int kk = 0; kk < 5; ++kk) { p2[it][kk] = __expf(sc[kk] - mx); sum += p2[it][kk]; }
        const float inv = 1.f / sum;
#pragma unroll
        for (int kk = 0; kk < 5; ++kk) p2[it][kk] *= inv;

        if (probs_base != nullptr) {
            const size_t pb = 16777216 + ((size_t)((bb * 8 + dil * 4 + g) * 2048 + s)) * 5;
            if (og) {
                float* pp = (float*)probs_base;
#pragma unroll
                for (int kk = 0; kk < 5; ++kk) pp[pb + kk] = p2[it][kk];
            } else {
                ushort_t* pp = (ushort_t*)probs_base;
#pragma unroll
                for (int kk = 0; kk < 5; ++kk) pp[pb + kk] = f2bf(p2[it][kk]);
            }
        }
    }

    // ---- stage C: swap in the V tile (scores already in regs)
    if (V != P) {
        __syncthreads();                      // all score reads done
#pragma unroll
        for (int i = 0; i < 10; ++i) {
            const int c = tid + 256 * i;
            const int tr = c >> 5, cc = c & 31;
            int s2 = s0 - 8 + tr; s2 = s2 < 0 ? 0 : (s2 > 2047 ? 2047 : s2);
            *reinterpret_cast<u32x4*>(&tile[tr * 256 + cc * 8]) =
                *reinterpret_cast<const u32x4*>(V + (rowbase + s2) * 256 + cc * 8);
        }
        __syncthreads();                      // V tile ready
    }

    // ---- PV for both dilations, packed to bf16 words in regs
    u32x4 wpk[2][4];
#pragma unroll
    for (int it = 0; it < 2; ++it) {
        const int dil  = it;
        const int dila = dil ? 1 : 3;
        const int ch0  = dil * 128 + g * 8;
        float o[4][8] = {};
#pragma unroll
        for (int kk = 0; kk < 5; ++kk) {
            const int sp = s + (kk - 2) * dila;
            if (sp < 0 || sp >= 2048) continue;
            const int tr2 = 8 + r + (kk - 2) * dila;
#pragma unroll
            for (int h = 0; h < 4; ++h) {
                bf16x8 t = load_bf8(&tile[tofs(tr2, ch0 + h * 32)]);
#pragma unroll
                for (int j = 0; j < 8; ++j) o[h][j] += p2[it][kk] * (float)t[j];
            }
        }
        // pack (channel d2 within the 32-ch group holds o[d2&3][d2>>2])
#pragma unroll
        for (int c = 0; c < 4; ++c) {
            u32x4 w;
#pragma unroll
            for (int t4 = 0; t4 < 4; ++t4) {
                const int d2a = c * 8 + t4 * 2, d2b = d2a + 1;
                const u32 lo = f2bf(o[d2a & 3][d2a >> 2]);
                const u32 hi = f2bf(o[d2b & 3][d2b >> 2]);
                w[t4] = lo | (hi << 16);
            }
            wpk[it][c] = w;
        }
    }
    __syncthreads();                          // ALL tile reads complete

    // write attention outputs into the tile (rows 8..71 = block rows 0..63)
#pragma unroll
    for (int it = 0; it < 2; ++it)
#pragma unroll
        for (int c = 0; c < 4; ++c)
            *reinterpret_cast<u32x4*>(&tile[tofs(8 + r, it * 128 + g * 32 + c * 8)]) = wpk[it][c];
    __syncthreads();                          // attn-out tile ready

    // ---- output GEMM (K=256) + bias + residual + LN epilogue ----
    const int n_off = wave * 64;

    f32x4 acc[4][4] = {};
    for (int kc = 0; kc < 8; ++kc) {
        bf16x8 a[4], b[4];
#pragma unroll
        for (int mt = 0; mt < 4; ++mt)
            a[mt] = load_bf8(&tile[tofs(8 + mt * 16 + l15, kc * 32 + quad * 8)]);
#pragma unroll
        for (int nt = 0; nt < 4; ++nt)
            b[nt] = load8_in(W, lw + (size_t)(n_off + nt * 16 + l15) * 256 + kc * 32 + quad * 8, wf);
#pragma unroll
        for (int mt = 0; mt < 4; ++mt)
#pragma unroll
            for (int nt = 0; nt < 4; ++nt)
                acc[mt][nt] = __builtin_amdgcn_mfma_f32_16x16x32_bf16(a[mt], b[nt], acc[mt][nt], 0, 0, 0);
    }

    float bias[4];
#pragma unroll
    for (int nt = 0; nt < 4; ++nt) bias[nt] = ld_in(Bv, lb + n_off + nt * 16 + l15, bvf);

    float psum[4][4] = {}, psq[4][4] = {};
#pragma unroll
    for (int mt = 0; mt < 4; ++mt) {
#pragma unroll
        for (int rr = 0; rr < 4; ++rr) {
            const size_t rrow = (size_t)(m0 + mt * 16 + quad * 4 + rr) * 256 + l15;
#pragma unroll
            for (int nt = 0; nt < 4; ++nt) {
                float v = acc[mt][nt][rr] + bias[nt] + ld_in(R, rrow + n_off + nt * 16, rf);
                acc[mt][nt][rr] = v;
                psum[mt][rr] += v;
                psq[mt][rr]  += v * v;
            }
        }
    }
#pragma unroll
    for (int off = 1; off <= 8; off <<= 1) {
#pragma unroll
        for (int mt = 0; mt < 4; ++mt)
#pragma unroll
            for (int rr = 0; rr < 4; ++rr) {
                psum[mt][rr] += __shfl_xor(psum[mt][rr], off);
                psq[mt][rr]  += __shfl_xor(psq[mt][rr],  off);
            }
    }
    if (l15 == 0) {
#pragma unroll
        for (int mt = 0; mt < 4; ++mt)
#pragma unroll
            for (int rr = 0; rr < 4; ++rr) {
                const int row = mt * 16 + quad * 4 + rr;
                lsum[wave][row] = psum[mt][rr];
                lsq[wave][row]  = psq[mt][rr];
            }
    }
    __syncthreads();

    float gl[4], blv[4];
#pragma unroll
    for (int nt = 0; nt < 4; ++nt) {
        gl[nt]  = ld_in(G,  lg + n_off + nt * 16 + l15, gf);
        blv[nt] = ld_in(Bt, lg + n_off + nt * 16 + l15, btf);
    }
#pragma unroll
    for (int mt = 0; mt < 4; ++mt) {
#pragma unroll
        for (int rr = 0; rr < 4; ++rr) {
            const int row = mt * 16 + quad * 4 + rr;
            const float sm = lsum[0][row] + lsum[1][row] + lsum[2][row] + lsum[3][row];
            const float q2 = lsq[0][row]  + lsq[1][row]  + lsq[2][row]  + lsq[3][row];
            const float mu  = sm * (1.f / 256.f);
            const float var = q2 * (1.f / 256.f) - mu * mu;
            const float rs  = rsqrtf(var + 1e-5f);
            const size_t hrow = (size_t)(m0 + row) * 256 + l15;
#pragma unroll
            for (int nt = 0; nt < 4; ++nt) {
                const float hv = (acc[mt][nt][rr] - mu) * rs * gl[nt] + blv[nt];
                if (of) ((float*)H)[hrow + n_off + nt * 16] = hv;
                else    ((ushort_t*)H)[hrow + n_off + nt * 16] = f2bf(hv);
            }
        }
    }
}

// ---------- launch ----------
extern "C" void kernel_launch(void* const* d_in, const int* in_sizes, int n_in,
                              void* d_out, int out_size, void* d_ws, size_t ws_size,
                              hipStream_t stream) {
    const void* q_emb = d_in[0];
    const void* s_emb = d_in[1];
    const void* W_lin = d_in[3];   // (3,2,128,128) layer stride 32768 elems
    const void* b_lin = d_in[4];   // (3,2,128)     layer stride 256
    const void* W_out = d_in[5];   // (3,256,256)   layer stride 65536
    const void* b_out = d_in[6];   // (3,256)       layer stride 256
    const void* ln_g  = d_in[7];
    const void* ln_b  = d_in[8];

    const size_t SLOT = 16777216;
    int*      flags = (int*)d_ws;                      // 16 ints
    ushort_t* SA = (ushort_t*)((char*)d_ws + 256);     // hq (bf16, row-major)
    ushort_t* SB = SA + SLOT;                          // hs (bf16, row-major -> swizzled after V-proj)
    ushort_t* SC = SA + 2 * SLOT;                      // proj scratch (bf16, swizzled)
    // d_ws footprint: 256 B + 3 x 33.55 MB = 100.7 MB (proved resident in earlier rounds)

    const dim3 blk(256);
    detect_kernel<<<1, blk, 0, stream>>>((const u32*)q_emb, 16384, flags + 0);
    detect_kernel<<<1, blk, 0, stream>>>((const u32*)s_emb, 16384, flags + 1);
    detect_kernel<<<1, blk, 0, stream>>>((const u32*)W_lin, 16384, flags + 3);
    detect_kernel<<<1, blk, 0, stream>>>((const u32*)b_lin,   384, flags + 4);
    detect_kernel<<<1, blk, 0, stream>>>((const u32*)W_out, 16384, flags + 5);
    detect_kernel<<<1, blk, 0, stream>>>((const u32*)b_out,   384, flags + 6);
    detect_kernel<<<1, blk, 0, stream>>>((const u32*)ln_g,    384, flags + 7);
    detect_kernel<<<1, blk, 0, stream>>>((const u32*)ln_b,    384, flags + 8);

    // ---- stage A: hq = LN(q_emb + mha(q_emb)) -> SA (bf16 row-major)
    proj_kernel<<<1024, blk, 0, stream>>>(q_emb, 0, W_lin, 0, b_lin, 0, SC, flags);
    fused_attn_oln_kernel<<<1024, blk, 0, stream>>>(SC, SC, q_emb, 0,
        W_out, 0, b_out, 0, ln_g, ln_b, 0, SA, 0, nullptr, flags);
    // ---- stage B: hs = LN(s_emb + mha(s_emb)) -> SB, probs -> d_out[16777216..]
    proj_kernel<<<1024, blk, 0, stream>>>(s_emb, 1, W_lin, 32768, b_lin, 256, SC, flags);
    fused_attn_oln_kernel<<<1024, blk, 0, stream>>>(SC, SC, s_emb, 1,
        W_out, 65536, b_out, 256, ln_g, ln_b, 256, SB, 0, d_out, flags);
    // ---- stage C: z = LN(hq + mha(q=k=hq, v=hs)) -> d_out (out dtype)
    proj_kernel<<<1024, blk, 0, stream>>>(SA, -1, W_lin, 65536, b_lin, 512, SC, flags);   // QK proj
    proj_kernel<<<1024, blk, 0, stream>>>(SB, -1, W_lin, 65536, b_lin, 512, SB, flags);   // V proj in-place
    fused_attn_oln_kernel<<<1024, blk, 0, stream>>>(SC, SB, SA, -1,
        W_out, 131072, b_out, 512, ln_g, ln_b, 512, d_out, 1, nullptr, flags);
}